// Round 2
// baseline (371.515 us; speedup 1.0000x reference)
//
#include <hip/hip_runtime.h>

// Fused self-attention, B=32, H=W=64, C=256.
// One WAVE per (b,c) chain; block = 4 waves = 4 channels; grid = 2048.
//
// vs previous version:
//  * blockIdx remap: 4 temporally-adjacent blocks on the SAME XCD cover the 4
//    channel-groups of one 64B cacheline with the same b -> output partial-line
//    writes merge in L2 (WRITE_SIZE 210->~135MB) and X reads share lines.
//  * K (M2->M3) handoff now fully in registers via the same permlane xchg as q
//    (M2 C-layout -> M3 B-frag is the identical index transform). No K LDS
//    round-trip; X tile stays intact in LDS.
//  * xf is NOT held through M3 (peak-register phase): M4 re-reads the X
//    fragments from LDS. Peak regs ~150 -> 3 waves/SIMD preserved.
//  * Phase A loads batched (8 float4 in flight); Wk fragments prefetched
//    depth-2 so L2 latency hides under M1/M2 MFMAs.

typedef short short8 __attribute__((ext_vector_type(8)));
typedef float floatx4 __attribute__((ext_vector_type(4)));
typedef unsigned int uint;

__device__ __forceinline__ uint cvtpk(float a, float b) {  // pack 2 bf16 (RNE)
  uint r;
  asm("v_cvt_pk_bf16_f32 %0, %1, %2" : "=v"(r) : "v"(a), "v"(b));
  return r;
}
__device__ __forceinline__ short8 u4s8(uint a, uint b, uint c, uint d) {
  union { uint u[4]; short8 s; } t;
  t.u[0] = a; t.u[1] = b; t.u[2] = c; t.u[3] = d;
  return t.s;
}
__device__ __forceinline__ float hsg(float x) {
  return fminf(fmaxf(0.2f * x + 0.5f, 0.f), 1.f);
}

// lo = [A_lanes0-31, C_lanes0-31], hi = [A_lanes32-63, C_lanes32-63]
__device__ __forceinline__ void pl32swap(uint A, uint C, uint& lo, uint& hi, int quad) {
#if __has_builtin(__builtin_amdgcn_permlane32_swap)
  auto r = __builtin_amdgcn_permlane32_swap(A, C, false, false);
  lo = (uint)r[0]; hi = (uint)r[1];
#else
  uint sA = __shfl_xor(A, 32), sC = __shfl_xor(C, 32);
  bool up = quad >= 2;
  lo = up ? sC : A;
  hi = up ? C : sA;
#endif
}
__device__ __forceinline__ void pl16swap(uint A, uint C, uint& lo, uint& hi, int quad) {
#if __has_builtin(__builtin_amdgcn_permlane16_swap)
  auto r = __builtin_amdgcn_permlane16_swap(A, C, false, false);
  lo = (uint)r[0]; hi = (uint)r[1];
#else
  uint sA = (uint)__builtin_amdgcn_ds_swizzle((int)A, 0x401F);
  uint sC = (uint)__builtin_amdgcn_ds_swizzle((int)C, 0x401F);
  bool odd = quad & 1;
  lo = odd ? sC : A;
  hi = odd ? C : sA;
#endif
}
// C-layout words (k-pair idx 8kt+2quad+r) -> A/B-frag short8 (k-pair idx 16ks+4quad+u)
__device__ __forceinline__ short8 xchg4(uint A, uint B, uint C, uint D, int quad) {
  uint Ap, Cp, Bp, Dp, t0, t1, t2, t3;
  pl32swap(A, C, Ap, Cp, quad);
  pl32swap(B, D, Bp, Dp, quad);
  pl16swap(Ap, Cp, t0, t2, quad);
  pl16swap(Bp, Dp, t1, t3, quad);
  return u4s8(t0, t1, t2, t3);
}

// ---- prep: Wq/Wk (C,64,64 f32) -> bf16 A-fragment layout in ws -------------
__global__ __launch_bounds__(256) void prep_w(const float* __restrict__ Wq,
                                              const float* __restrict__ Wk,
                                              unsigned short* __restrict__ ws) {
  __shared__ __align__(16) unsigned char sm[4 * 8704];
  const int tid = threadIdx.x, lane = tid & 63, wid = tid >> 6;
  const int task = blockIdx.x * 4 + wid;              // [0, 512)
  const int c = task & 255;
  const float* wp = ((task >> 8) ? Wk : Wq) + (size_t)c * 4096;
  unsigned char* buf = sm + wid * 8704;
  const int l15 = lane & 15, quad = lane >> 4;
#pragma unroll 4
  for (int j = 0; j < 16; ++j) {                      // stage [w][k], stride 136 B
    int f4 = j * 64 + lane;
    float4 v = *(const float4*)(wp + (size_t)f4 * 4);
    int w = f4 >> 4, k0 = (f4 & 15) << 2;
    uint2 pk; pk.x = cvtpk(v.x, v.y); pk.y = cvtpk(v.z, v.w);
    *(uint2*)(buf + w * 136 + k0 * 2) = pk;
  }
  unsigned short* dst = ws + (size_t)task * 4096;
#pragma unroll
  for (int kt = 0; kt < 4; ++kt)
#pragma unroll
    for (int ks = 0; ks < 2; ++ks) {                  // transposed u16 gather
      const unsigned short* p = (const unsigned short*)buf + (ks * 32 + quad * 8) * 68 + (kt * 16 + l15);
      short8 af = u4s8((uint)p[0]   | ((uint)p[68]  << 16),
                       (uint)p[136] | ((uint)p[204] << 16),
                       (uint)p[272] | ((uint)p[340] << 16),
                       (uint)p[408] | ((uint)p[476] << 16));
      *(short8*)(dst + ((kt * 2 + ks) * 64 + lane) * 8) = af;
    }
}

// ---- main ------------------------------------------------------------------
__global__ __launch_bounds__(256, 3) void fused_attn(
    const float* __restrict__ x, const unsigned short* __restrict__ wsp,
    float* __restrict__ out) {
  __shared__ __align__(16) unsigned char smem[4 * 8192];

  const int tid  = threadIdx.x;
  const int lane = tid & 63;
  const int wid  = tid >> 6;
  const int l15  = lane & 15;
  const int quad = lane >> 4;

  // ---- block remap: 4 consecutive same-XCD slots = same b, 4 cgs of one cg4
  // (jointly cover full 64B lines of x reads and out writes; weights for a
  //  cg4 confined to one XCD's L2).
  const int p    = blockIdx.x;
  const int xcd  = p & 7;
  const int slot = p >> 3;                  // 0..255, consecutive slots adjacent in time
  const int cg4  = xcd * 2 + (slot >> 7);   // 16 groups of 16 channels
  const int b    = (slot >> 2) & 31;
  const int cg   = (cg4 << 2) + (slot & 3);
  const int c0   = cg << 2;
  const int c    = c0 + wid;

  unsigned char* buf0 = smem + wid * 8192;

  const short8* wqf = (const short8*)wsp + (size_t)c * 512;
  const short8* wkf = wqf + 256 * 512;

  // prefetch Wq fragments (in flight during X staging + barrier)
  short8 aq[4][2];
#pragma unroll
  for (int kt = 0; kt < 4; ++kt)
#pragma unroll
    for (int ks = 0; ks < 2; ++ks) aq[kt][ks] = wqf[(kt * 2 + ks) * 64 + lane];

  // ---- Phase A: cooperative X staging, batched loads -> b32 LDS stores -----
  {
    const float* xb = x + (size_t)b * 4096 * 256 + c0;
#pragma unroll
    for (int bat = 0; bat < 2; ++bat) {
      float4 va[4], vb[4];
#pragma unroll
      for (int i = 0; i < 4; ++i) {                   // 8 loads in flight
        int p4 = (bat * 4 + i) * 256 + tid;
        int h = p4 >> 5, w0 = (p4 & 31) << 1;
        const float* src = xb + (size_t)(h * 64 + w0) * 256;
        va[i] = *(const float4*)src;
        vb[i] = *(const float4*)(src + 256);
      }
#pragma unroll
      for (int i = 0; i < 4; ++i) {
        int p4 = (bat * 4 + i) * 256 + tid;
        int h = p4 >> 5, w0 = (p4 & 31) << 1;
        uint off = (uint)(h * 128 + (((w0 >> 3) ^ (h & 7)) << 4) + ((w0 & 7) << 1));
        *(uint*)(smem + 0 * 8192 + off) = cvtpk(va[i].x, vb[i].x);
        *(uint*)(smem + 1 * 8192 + off) = cvtpk(va[i].y, vb[i].y);
        *(uint*)(smem + 2 * 8192 + off) = cvtpk(va[i].z, vb[i].z);
        *(uint*)(smem + 3 * 8192 + off) = cvtpk(va[i].w, vb[i].w);
      }
    }
  }
  __syncthreads();

  // ---- X fragments -> registers (B-operand layout) -------------------------
  short8 xf[4][2];
#pragma unroll
  for (int rt = 0; rt < 4; ++rt) {
    int r = rt * 16 + l15;
#pragma unroll
    for (int ks = 0; ks < 2; ++ks)
      xf[rt][ks] = *(const short8*)(buf0 + r * 128 + (((ks * 4 + quad) ^ (r & 7)) << 4));
  }

  // Wk depth-2 prefetch: kt=0,1 issued now (hide under M1 MFMAs)
  short8 wkp[2][2];
  wkp[0][0] = wkf[0 * 64 + lane]; wkp[0][1] = wkf[1 * 64 + lane];
  wkp[1][0] = wkf[2 * 64 + lane]; wkp[1][1] = wkf[3 * 64 + lane];

  const floatx4 zero4 = {0.f, 0.f, 0.f, 0.f};
  floatx4 acc[16];

  // ==== M1: qT = WqT x X (acc: k = kt*16+quad*4+i, h = ht*16+l15) ===========
#pragma unroll
  for (int i = 0; i < 16; ++i) acc[i] = zero4;
  __builtin_amdgcn_s_setprio(1);
#pragma unroll
  for (int kt = 0; kt < 4; ++kt)
#pragma unroll
    for (int ht = 0; ht < 4; ++ht) {
      acc[kt * 4 + ht] = __builtin_amdgcn_mfma_f32_16x16x32_bf16(aq[kt][0], xf[ht][0], acc[kt * 4 + ht], 0, 0, 0);
      acc[kt * 4 + ht] = __builtin_amdgcn_mfma_f32_16x16x32_bf16(aq[kt][1], xf[ht][1], acc[kt * 4 + ht], 0, 0, 0);
    }
  __builtin_amdgcn_s_setprio(0);

  // hard_sigmoid + in-register exchange -> qf[ht][ks] (A-frag)
  short8 qf[4][2];
#pragma unroll
  for (int ht = 0; ht < 4; ++ht) {
    uint s[4][2];
#pragma unroll
    for (int kt = 0; kt < 4; ++kt) {
      floatx4 a = acc[kt * 4 + ht];
      s[kt][0] = cvtpk(hsg(a[0]), hsg(a[1]));
      s[kt][1] = cvtpk(hsg(a[2]), hsg(a[3]));
    }
#pragma unroll
    for (int ks = 0; ks < 2; ++ks)
      qf[ht][ks] = xchg4(s[2 * ks][0], s[2 * ks][1], s[2 * ks + 1][0], s[2 * ks + 1][1], quad);
  }

  // ==== M2: KT = WkT x X (acc: k = kt*16+quad*4+i, m = ht*16+l15) ===========
#pragma unroll
  for (int i = 0; i < 16; ++i) acc[i] = zero4;
#pragma unroll
  for (int kt = 0; kt < 4; ++kt) {
    short8 a0 = wkp[kt & 1][0], a1 = wkp[kt & 1][1];
    if (kt < 2) {                                     // prefetch kt+2
      wkp[kt & 1][0] = wkf[((kt + 2) * 2 + 0) * 64 + lane];
      wkp[kt & 1][1] = wkf[((kt + 2) * 2 + 1) * 64 + lane];
    }
    __builtin_amdgcn_s_setprio(1);
#pragma unroll
    for (int ht = 0; ht < 4; ++ht) {
      acc[kt * 4 + ht] = __builtin_amdgcn_mfma_f32_16x16x32_bf16(a0, xf[ht][0], acc[kt * 4 + ht], 0, 0, 0);
      acc[kt * 4 + ht] = __builtin_amdgcn_mfma_f32_16x16x32_bf16(a1, xf[ht][1], acc[kt * 4 + ht], 0, 0, 0);
    }
    __builtin_amdgcn_s_setprio(0);
  }
  // tanh + in-register exchange -> kf[ht][ks] (B-frag for M3; same transform as qf)
  short8 kf[4][2];
#pragma unroll
  for (int ht = 0; ht < 4; ++ht) {
    uint t[4][2];
#pragma unroll
    for (int kt = 0; kt < 4; ++kt) {
      floatx4 a = acc[kt * 4 + ht];
      float kv[4];
#pragma unroll
      for (int i = 0; i < 4; ++i) {
        float e = __expf(2.f * a[i]);
        kv[i] = 1.f - 2.f / (e + 1.f);                // tanh
      }
      t[kt][0] = cvtpk(kv[0], kv[1]);
      t[kt][1] = cvtpk(kv[2], kv[3]);
    }
#pragma unroll
    for (int ks = 0; ks < 2; ++ks)
      kf[ht][ks] = xchg4(t[2 * ks][0], t[2 * ks][1], t[2 * ks + 1][0], t[2 * ks + 1][1], quad);
  }
  // NOTE: xf intentionally dead here (re-read in M4) to cap M3 register peak.

  // ==== M3: S = q x K^T (acc: w = wt*16+quad*4+i, m = mt*16+l15) ============
#pragma unroll
  for (int i = 0; i < 16; ++i) acc[i] = zero4;
  __builtin_amdgcn_s_setprio(1);
#pragma unroll
  for (int mt = 0; mt < 4; ++mt)
#pragma unroll
    for (int wt = 0; wt < 4; ++wt) {
      acc[wt * 4 + mt] = __builtin_amdgcn_mfma_f32_16x16x32_bf16(qf[wt][0], kf[mt][0], acc[wt * 4 + mt], 0, 0, 0);
      acc[wt * 4 + mt] = __builtin_amdgcn_mfma_f32_16x16x32_bf16(qf[wt][1], kf[mt][1], acc[wt * 4 + mt], 0, 0, 0);
    }
  __builtin_amdgcn_s_setprio(0);

  // e = exp(hs(s)); hs in [0,1] -> no max subtraction needed
#pragma unroll
  for (int i = 0; i < 16; ++i)
#pragma unroll
    for (int j = 0; j < 4; ++j) acc[i][j] = __expf(hsg(acc[i][j]));
  float inv[4][4];
#pragma unroll
  for (int wt = 0; wt < 4; ++wt)
#pragma unroll
    for (int i = 0; i < 4; ++i) {                     // row sum: 3 adds + 4 shfls
      float pp = acc[wt * 4 + 0][i] + acc[wt * 4 + 1][i] + acc[wt * 4 + 2][i] + acc[wt * 4 + 3][i];
      pp += __shfl_xor(pp, 1, 16);
      pp += __shfl_xor(pp, 2, 16);
      pp += __shfl_xor(pp, 4, 16);
      pp += __shfl_xor(pp, 8, 16);
      inv[wt][i] = 1.f / pp;
    }
  // normalize + in-register exchange -> sf[mt][ks] (A-frag: m=mt*16+l15, k=w)
  short8 sf[4][2];
#pragma unroll
  for (int mt = 0; mt < 4; ++mt) {
    uint s[4][2];
#pragma unroll
    for (int wt = 0; wt < 4; ++wt) {
      floatx4 a = acc[wt * 4 + mt];
      s[wt][0] = cvtpk(a[0] * inv[wt][0], a[1] * inv[wt][1]);
      s[wt][1] = cvtpk(a[2] * inv[wt][2], a[3] * inv[wt][3]);
    }
#pragma unroll
    for (int ks = 0; ks < 2; ++ks)
      sf[mt][ks] = xchg4(s[2 * ks][0], s[2 * ks][1], s[2 * ks + 1][0], s[2 * ks + 1][1], quad);
  }

  // ==== M4: outT = SnT x X (X re-read from intact LDS) ======================
  short8 xg[4][2];
#pragma unroll
  for (int rt = 0; rt < 4; ++rt) {
    int r = rt * 16 + l15;
#pragma unroll
    for (int ks = 0; ks < 2; ++ks)
      xg[rt][ks] = *(const short8*)(buf0 + r * 128 + (((ks * 4 + quad) ^ (r & 7)) << 4));
  }
#pragma unroll
  for (int i = 0; i < 16; ++i) acc[i] = zero4;
  __builtin_amdgcn_s_setprio(1);
#pragma unroll
  for (int mt = 0; mt < 4; ++mt)
#pragma unroll
    for (int ht = 0; ht < 4; ++ht) {
      acc[mt * 4 + ht] = __builtin_amdgcn_mfma_f32_16x16x32_bf16(sf[mt][0], xg[ht][0], acc[mt * 4 + ht], 0, 0, 0);
      acc[mt * 4 + ht] = __builtin_amdgcn_mfma_f32_16x16x32_bf16(sf[mt][1], xg[ht][1], acc[mt * 4 + ht], 0, 0, 0);
    }
  __builtin_amdgcn_s_setprio(0);
#pragma unroll
  for (int mt = 0; mt < 4; ++mt)
#pragma unroll
    for (int ht = 0; ht < 4; ++ht) {                  // lane: fixed h, 4 consecutive m
      floatx4 a = acc[mt * 4 + ht];
      uint2 pk; pk.x = cvtpk(a[0], a[1]); pk.y = cvtpk(a[2], a[3]);
      int h = ht * 16 + l15;
      *(uint2*)(buf0 + h * 128 + ((((mt * 2 + (quad >> 1)) ^ (h & 7))) << 4) + ((quad & 1) << 3)) = pk;
    }
  __syncthreads();

  // ---- Phase C: cooperative output (b64 slot reads, float4 global stores) --
  const size_t outbase = (size_t)b * 4096 * 256 + c0;
#pragma unroll
  for (int rep = 0; rep < 4; ++rep) {
    int idx = rep * 256 + tid;
    int h = idx >> 4, mq = idx & 15;                  // m0 = mq*4
    uint loff = (uint)(h * 128 + ((((mq >> 1) ^ (h & 7))) << 4) + ((mq & 1) << 3));
    float vals[4][4];
#pragma unroll
    for (int j = 0; j < 4; ++j) {
      uint2 d = *(const uint2*)(smem + j * 8192 + loff);
      vals[j][0] = __uint_as_float(d.x << 16);
      vals[j][1] = __uint_as_float(d.x & 0xFFFF0000u);
      vals[j][2] = __uint_as_float(d.y << 16);
      vals[j][3] = __uint_as_float(d.y & 0xFFFF0000u);
    }
    float* op = out + outbase + (size_t)(h * 64 + mq * 4) * 256;
#pragma unroll
    for (int jj = 0; jj < 4; ++jj) {
      float4 v = {vals[0][jj], vals[1][jj], vals[2][jj], vals[3][jj]};
      *(float4*)(op + (size_t)jj * 256) = v;
    }
  }
}

extern "C" void kernel_launch(void* const* d_in, const int* in_sizes, int n_in,
                              void* d_out, int out_size, void* d_ws, size_t ws_size,
                              hipStream_t stream) {
  const float* x  = (const float*)d_in[0];
  const float* Wq = (const float*)d_in[1];
  const float* Wk = (const float*)d_in[2];
  unsigned short* ws = (unsigned short*)d_ws;  // 4 MiB used
  prep_w<<<dim3(128), dim3(256), 0, stream>>>(Wq, Wk, ws);
  fused_attn<<<dim3(2048), dim3(256), 0, stream>>>(x, ws, (float*)d_out);
}

// Round 3
// 285.035 us; speedup vs baseline: 1.3034x; 1.3034x over previous
//
#include <hip/hip_runtime.h>

// Fused self-attention, B=32, H=W=64, C=256.
// One WAVE per (b,c) chain; block = 16 waves = 16 channels (1024 thr); grid = 512.
//
// vs previous version:
//  * REVERTED the XCD blockIdx remap (r2: FETCH doubled -> mapping assumption wrong).
//  * Block now owns the 16 channels of one 64B cacheline: Phase A reads and
//    Phase C writes touch only FULL exclusive lines -> no dependence on
//    cross-block L2 merging. Ideal traffic ~134MB each way.
//  * 16 waves x 8KB = 128KB LDS -> 1 block/CU -> 16 waves/CU (4/SIMD, was 12).
//  * Register diet to fit 128 regs (4 waves/SIMD hard cap):
//    - M1/M4 ht-outer, X fragments streamed from LDS (8 live, not 32)
//    - M2 kt-outer, wk single-buffer, X re-streamed per use
//    - M3 split into two wt-half passes (acc 32, not 64); softmax row-sums are
//      per-wt and sf[mt][ks] depends only on wt-pair {2ks,2ks+1} -> exact split.
//  * K handoff stays fully in registers (permlane xchg, verified r2).

typedef short short8 __attribute__((ext_vector_type(8)));
typedef float floatx4 __attribute__((ext_vector_type(4)));
typedef unsigned int uint;

__device__ __forceinline__ uint cvtpk(float a, float b) {  // pack 2 bf16 (RNE)
  uint r;
  asm("v_cvt_pk_bf16_f32 %0, %1, %2" : "=v"(r) : "v"(a), "v"(b));
  return r;
}
__device__ __forceinline__ short8 u4s8(uint a, uint b, uint c, uint d) {
  union { uint u[4]; short8 s; } t;
  t.u[0] = a; t.u[1] = b; t.u[2] = c; t.u[3] = d;
  return t.s;
}
__device__ __forceinline__ float hsg(float x) {
  return fminf(fmaxf(0.2f * x + 0.5f, 0.f), 1.f);
}

__device__ __forceinline__ void pl32swap(uint A, uint C, uint& lo, uint& hi, int quad) {
#if __has_builtin(__builtin_amdgcn_permlane32_swap)
  auto r = __builtin_amdgcn_permlane32_swap(A, C, false, false);
  lo = (uint)r[0]; hi = (uint)r[1];
#else
  uint sA = __shfl_xor(A, 32), sC = __shfl_xor(C, 32);
  bool up = quad >= 2;
  lo = up ? sC : A;
  hi = up ? C : sA;
#endif
}
__device__ __forceinline__ void pl16swap(uint A, uint C, uint& lo, uint& hi, int quad) {
#if __has_builtin(__builtin_amdgcn_permlane16_swap)
  auto r = __builtin_amdgcn_permlane16_swap(A, C, false, false);
  lo = (uint)r[0]; hi = (uint)r[1];
#else
  uint sA = (uint)__builtin_amdgcn_ds_swizzle((int)A, 0x401F);
  uint sC = (uint)__builtin_amdgcn_ds_swizzle((int)C, 0x401F);
  bool odd = quad & 1;
  lo = odd ? sC : A;
  hi = odd ? C : sA;
#endif
}
// C-layout words (k-pair idx 8kt+2quad+r) -> A/B-frag short8 (k-pair idx 16ks+4quad+u)
__device__ __forceinline__ short8 xchg4(uint A, uint B, uint C, uint D, int quad) {
  uint Ap, Cp, Bp, Dp, t0, t1, t2, t3;
  pl32swap(A, C, Ap, Cp, quad);
  pl32swap(B, D, Bp, Dp, quad);
  pl16swap(Ap, Cp, t0, t2, quad);
  pl16swap(Bp, Dp, t1, t3, quad);
  return u4s8(t0, t1, t2, t3);
}

// ---- prep: Wq/Wk (C,64,64 f32) -> bf16 A-fragment layout in ws -------------
__global__ __launch_bounds__(256) void prep_w(const float* __restrict__ Wq,
                                              const float* __restrict__ Wk,
                                              unsigned short* __restrict__ ws) {
  __shared__ __align__(16) unsigned char sm[4 * 8704];
  const int tid = threadIdx.x, lane = tid & 63, wid = tid >> 6;
  const int task = blockIdx.x * 4 + wid;              // [0, 512)
  const int c = task & 255;
  const float* wp = ((task >> 8) ? Wk : Wq) + (size_t)c * 4096;
  unsigned char* buf = sm + wid * 8704;
  const int l15 = lane & 15, quad = lane >> 4;
#pragma unroll 4
  for (int j = 0; j < 16; ++j) {                      // stage [w][k], stride 136 B
    int f4 = j * 64 + lane;
    float4 v = *(const float4*)(wp + (size_t)f4 * 4);
    int w = f4 >> 4, k0 = (f4 & 15) << 2;
    uint2 pk; pk.x = cvtpk(v.x, v.y); pk.y = cvtpk(v.z, v.w);
    *(uint2*)(buf + w * 136 + k0 * 2) = pk;
  }
  unsigned short* dst = ws + (size_t)task * 4096;
#pragma unroll
  for (int kt = 0; kt < 4; ++kt)
#pragma unroll
    for (int ks = 0; ks < 2; ++ks) {                  // transposed u16 gather
      const unsigned short* p = (const unsigned short*)buf + (ks * 32 + quad * 8) * 68 + (kt * 16 + l15);
      short8 af = u4s8((uint)p[0]   | ((uint)p[68]  << 16),
                       (uint)p[136] | ((uint)p[204] << 16),
                       (uint)p[272] | ((uint)p[340] << 16),
                       (uint)p[408] | ((uint)p[476] << 16));
      *(short8*)(dst + ((kt * 2 + ks) * 64 + lane) * 8) = af;
    }
}

// ---- main ------------------------------------------------------------------
__global__ __launch_bounds__(1024, 4) void fused_attn(
    const float* __restrict__ x, const unsigned short* __restrict__ wsp,
    float* __restrict__ out) {
  __shared__ __align__(16) unsigned char smem[16 * 8192];   // 128 KiB

  const int tid  = threadIdx.x;
  const int lane = tid & 63;
  const int wid  = tid >> 6;                 // 0..15 = channel within line
  const int l15  = lane & 15;
  const int quad = lane >> 4;

  const int b    = blockIdx.x & 31;          // b inner: 32 blocks share weights
  const int cg16 = blockIdx.x >> 5;          // 16 groups of 16 channels
  const int c0   = cg16 << 4;
  const int c    = c0 + wid;

  unsigned char* buf0 = smem + wid * 8192;

  const short8* wqf = (const short8*)wsp + (size_t)c * 512;
  const short8* wkf = wqf + 256 * 512;

  // prefetch Wq fragments (in flight during X staging + barrier)
  short8 aq[4][2];
#pragma unroll
  for (int kt = 0; kt < 4; ++kt)
#pragma unroll
    for (int ks = 0; ks < 2; ++ks) aq[kt][ks] = wqf[(kt * 2 + ks) * 64 + lane];

  // ---- Phase A: cooperative X staging; full exclusive 64B lines ------------
  // thread t: channels c0 + (t&3)*4 .. +3 of position-pair grp = t>>2.
  {
    const int ch4 = tid & 3, grp = tid >> 2;
    const float* xb = x + (size_t)b * 4096 * 256 + c0 + ch4 * 4;
#pragma unroll
    for (int bat = 0; bat < 2; ++bat) {
      float4 va[4], vb[4];
#pragma unroll
      for (int i = 0; i < 4; ++i) {                   // 8 loads in flight
        int pair = (bat * 4 + i) * 256 + grp;
        int h = pair >> 5, w0 = (pair & 31) << 1;
        const float* src = xb + (size_t)(h * 64 + w0) * 256;
        va[i] = *(const float4*)src;
        vb[i] = *(const float4*)(src + 256);
      }
#pragma unroll
      for (int i = 0; i < 4; ++i) {
        int pair = (bat * 4 + i) * 256 + grp;
        int h = pair >> 5, w0 = (pair & 31) << 1;
        uint off = (uint)(h * 128 + (((w0 >> 3) ^ (h & 7)) << 4) + ((w0 & 7) << 1));
        unsigned char* base = smem + (size_t)(ch4 * 4) * 8192 + off;
        *(uint*)(base + 0 * 8192) = cvtpk(va[i].x, vb[i].x);
        *(uint*)(base + 1 * 8192) = cvtpk(va[i].y, vb[i].y);
        *(uint*)(base + 2 * 8192) = cvtpk(va[i].z, vb[i].z);
        *(uint*)(base + 3 * 8192) = cvtpk(va[i].w, vb[i].w);
      }
    }
  }
  __syncthreads();

  const floatx4 zero4 = {0.f, 0.f, 0.f, 0.f};
  floatx4 acc[16];

  // ==== M1: qT = WqT x X (ht-outer, X streamed from LDS) ====================
#pragma unroll
  for (int i = 0; i < 16; ++i) acc[i] = zero4;
#pragma unroll
  for (int ht = 0; ht < 4; ++ht) {
    int r = ht * 16 + l15;
    short8 x0 = *(const short8*)(buf0 + r * 128 + (((quad) ^ (r & 7)) << 4));
    short8 x1 = *(const short8*)(buf0 + r * 128 + (((4 + quad) ^ (r & 7)) << 4));
    __builtin_amdgcn_s_setprio(1);
#pragma unroll
    for (int kt = 0; kt < 4; ++kt) {
      acc[kt * 4 + ht] = __builtin_amdgcn_mfma_f32_16x16x32_bf16(aq[kt][0], x0, acc[kt * 4 + ht], 0, 0, 0);
      acc[kt * 4 + ht] = __builtin_amdgcn_mfma_f32_16x16x32_bf16(aq[kt][1], x1, acc[kt * 4 + ht], 0, 0, 0);
    }
    __builtin_amdgcn_s_setprio(0);
  }

  // hard_sigmoid + in-register exchange -> qf[ht][ks] (A-frag); aq dies here
  short8 qf[4][2];
#pragma unroll
  for (int ht = 0; ht < 4; ++ht) {
    uint s[4][2];
#pragma unroll
    for (int kt = 0; kt < 4; ++kt) {
      floatx4 a = acc[kt * 4 + ht];
      s[kt][0] = cvtpk(hsg(a[0]), hsg(a[1]));
      s[kt][1] = cvtpk(hsg(a[2]), hsg(a[3]));
    }
#pragma unroll
    for (int ks = 0; ks < 2; ++ks)
      qf[ht][ks] = xchg4(s[2 * ks][0], s[2 * ks][1], s[2 * ks + 1][0], s[2 * ks + 1][1], quad);
  }

  // ==== M2: KT = WkT x X (kt-outer, wk single-buffer, X re-streamed) ========
#pragma unroll
  for (int i = 0; i < 16; ++i) acc[i] = zero4;
#pragma unroll
  for (int kt = 0; kt < 4; ++kt) {
    short8 a0 = wkf[(kt * 2 + 0) * 64 + lane];
    short8 a1 = wkf[(kt * 2 + 1) * 64 + lane];
    __builtin_amdgcn_s_setprio(1);
#pragma unroll
    for (int ht = 0; ht < 4; ++ht) {
      int r = ht * 16 + l15;
      short8 x0 = *(const short8*)(buf0 + r * 128 + (((quad) ^ (r & 7)) << 4));
      short8 x1 = *(const short8*)(buf0 + r * 128 + (((4 + quad) ^ (r & 7)) << 4));
      acc[kt * 4 + ht] = __builtin_amdgcn_mfma_f32_16x16x32_bf16(a0, x0, acc[kt * 4 + ht], 0, 0, 0);
      acc[kt * 4 + ht] = __builtin_amdgcn_mfma_f32_16x16x32_bf16(a1, x1, acc[kt * 4 + ht], 0, 0, 0);
    }
    __builtin_amdgcn_s_setprio(0);
  }
  // tanh + in-register exchange -> kf[ht][ks] (B-frag for M3)
  short8 kf[4][2];
#pragma unroll
  for (int ht = 0; ht < 4; ++ht) {
    uint t[4][2];
#pragma unroll
    for (int kt = 0; kt < 4; ++kt) {
      floatx4 a = acc[kt * 4 + ht];
      float kv[4];
#pragma unroll
      for (int i = 0; i < 4; ++i) {
        float e = __expf(2.f * a[i]);
        kv[i] = 1.f - 2.f / (e + 1.f);                // tanh
      }
      t[kt][0] = cvtpk(kv[0], kv[1]);
      t[kt][1] = cvtpk(kv[2], kv[3]);
    }
#pragma unroll
    for (int ks = 0; ks < 2; ++ks)
      kf[ht][ks] = xchg4(t[2 * ks][0], t[2 * ks][1], t[2 * ks + 1][0], t[2 * ks + 1][1], quad);
  }

  // ==== M3: S = q x K^T, softmax; TWO wt-half passes (acc 32 regs) ==========
  // Row-sums are per-wt; sf[mt][ks2] depends only on wt in {2ks2, 2ks2+1}.
  short8 sf[4][2];
#pragma unroll
  for (int ks2 = 0; ks2 < 2; ++ks2) {
    floatx4 a2[8];
#pragma unroll
    for (int i = 0; i < 8; ++i) a2[i] = zero4;
    __builtin_amdgcn_s_setprio(1);
#pragma unroll
    for (int mt = 0; mt < 4; ++mt)
#pragma unroll
      for (int wtl = 0; wtl < 2; ++wtl) {
        int wt = ks2 * 2 + wtl;
        a2[wtl * 4 + mt] = __builtin_amdgcn_mfma_f32_16x16x32_bf16(qf[wt][0], kf[mt][0], a2[wtl * 4 + mt], 0, 0, 0);
        a2[wtl * 4 + mt] = __builtin_amdgcn_mfma_f32_16x16x32_bf16(qf[wt][1], kf[mt][1], a2[wtl * 4 + mt], 0, 0, 0);
      }
    __builtin_amdgcn_s_setprio(0);
    // e = exp(hs(s)); hs in [0,1] -> no max subtraction needed
#pragma unroll
    for (int i = 0; i < 8; ++i)
#pragma unroll
      for (int j = 0; j < 4; ++j) a2[i][j] = __expf(hsg(a2[i][j]));
    float inv2[2][4];
#pragma unroll
    for (int wtl = 0; wtl < 2; ++wtl)
#pragma unroll
      for (int i = 0; i < 4; ++i) {                   // row sum: 3 adds + 4 shfls
        float pp = a2[wtl * 4 + 0][i] + a2[wtl * 4 + 1][i] + a2[wtl * 4 + 2][i] + a2[wtl * 4 + 3][i];
        pp += __shfl_xor(pp, 1, 16);
        pp += __shfl_xor(pp, 2, 16);
        pp += __shfl_xor(pp, 4, 16);
        pp += __shfl_xor(pp, 8, 16);
        inv2[wtl][i] = 1.f / pp;
      }
#pragma unroll
    for (int mt = 0; mt < 4; ++mt) {
      uint s0 = cvtpk(a2[mt][0] * inv2[0][0], a2[mt][1] * inv2[0][1]);
      uint s1 = cvtpk(a2[mt][2] * inv2[0][2], a2[mt][3] * inv2[0][3]);
      uint s2 = cvtpk(a2[4 + mt][0] * inv2[1][0], a2[4 + mt][1] * inv2[1][1]);
      uint s3 = cvtpk(a2[4 + mt][2] * inv2[1][2], a2[4 + mt][3] * inv2[1][3]);
      sf[mt][ks2] = xchg4(s0, s1, s2, s3, quad);
    }
  }

  // ==== M4: outT = SnT x X (ht-outer, X streamed; then out -> buf0) =========
#pragma unroll
  for (int i = 0; i < 16; ++i) acc[i] = zero4;
#pragma unroll
  for (int ht = 0; ht < 4; ++ht) {
    int r = ht * 16 + l15;
    short8 x0 = *(const short8*)(buf0 + r * 128 + (((quad) ^ (r & 7)) << 4));
    short8 x1 = *(const short8*)(buf0 + r * 128 + (((4 + quad) ^ (r & 7)) << 4));
    __builtin_amdgcn_s_setprio(1);
#pragma unroll
    for (int mt = 0; mt < 4; ++mt) {
      acc[mt * 4 + ht] = __builtin_amdgcn_mfma_f32_16x16x32_bf16(sf[mt][0], x0, acc[mt * 4 + ht], 0, 0, 0);
      acc[mt * 4 + ht] = __builtin_amdgcn_mfma_f32_16x16x32_bf16(sf[mt][1], x1, acc[mt * 4 + ht], 0, 0, 0);
    }
    __builtin_amdgcn_s_setprio(0);
  }
#pragma unroll
  for (int mt = 0; mt < 4; ++mt)
#pragma unroll
    for (int ht = 0; ht < 4; ++ht) {                  // lane: fixed h, 4 consecutive m
      floatx4 a = acc[mt * 4 + ht];
      uint2 pk; pk.x = cvtpk(a[0], a[1]); pk.y = cvtpk(a[2], a[3]);
      int h = ht * 16 + l15;
      *(uint2*)(buf0 + h * 128 + ((((mt * 2 + (quad >> 1)) ^ (h & 7))) << 4) + ((quad & 1) << 3)) = pk;
    }
  __syncthreads();

  // ---- Phase C: cooperative output; full exclusive 64B lines ---------------
  {
    const int ch4 = tid & 3, grp = tid >> 2;
    const size_t outbase = (size_t)b * 4096 * 256 + c0 + ch4 * 4;
#pragma unroll
    for (int rep = 0; rep < 4; ++rep) {
      int qidx = rep * 256 + grp;
      int h = qidx >> 4, mq = qidx & 15;              // m0 = mq*4
      uint loff = (uint)(h * 128 + ((((mq >> 1) ^ (h & 7))) << 4) + ((mq & 1) << 3));
      float vals[4][4];
#pragma unroll
      for (int j = 0; j < 4; ++j) {
        uint2 d = *(const uint2*)(smem + (size_t)(ch4 * 4 + j) * 8192 + loff);
        vals[j][0] = __uint_as_float(d.x << 16);
        vals[j][1] = __uint_as_float(d.x & 0xFFFF0000u);
        vals[j][2] = __uint_as_float(d.y << 16);
        vals[j][3] = __uint_as_float(d.y & 0xFFFF0000u);
      }
      float* op = out + outbase + (size_t)(h * 64 + mq * 4) * 256;
#pragma unroll
      for (int jj = 0; jj < 4; ++jj) {
        float4 v = {vals[0][jj], vals[1][jj], vals[2][jj], vals[3][jj]};
        *(float4*)(op + (size_t)jj * 256) = v;
      }
    }
  }
}

extern "C" void kernel_launch(void* const* d_in, const int* in_sizes, int n_in,
                              void* d_out, int out_size, void* d_ws, size_t ws_size,
                              hipStream_t stream) {
  const float* x  = (const float*)d_in[0];
  const float* Wq = (const float*)d_in[1];
  const float* Wk = (const float*)d_in[2];
  unsigned short* ws = (unsigned short*)d_ws;  // 4 MiB used
  prep_w<<<dim3(128), dim3(256), 0, stream>>>(Wq, Wk, ws);
  fused_attn<<<dim3(512), dim3(1024), 0, stream>>>(x, ws, (float*)d_out);
}